// Round 14
// baseline (72.808 us; speedup 1.0000x reference)
//
#include <hip/hip_runtime.h>
#include <math.h>

#define NB 4
#define NPRED 8400
#define NGT 32
#define NCLS 80
#define ROW 85
#define NSEG 132    // ceil(8400/64); last segment has 16 preds

typedef unsigned long long u64;

// ---------- math helpers (mirror reference fp32 op order) ----------

__device__ __forceinline__ float focal_t(float x, float t) {
    float p = 1.f / (1.f + expf(-x));
    float ce = (fmaxf(x, 0.f) + log1pf(expf(-fabsf(x)))) - x * t; // logaddexp(0,x) - x*t
    float pt = p * t + (1.f - p) * (1.f - t);
    float ompt = 1.f - pt;
    float loss = ce * (ompt * ompt);              // GAMMA=2
    float at = 0.25f * t + 0.75f * (1.f - t);     // ALPHA=0.25
    return at * loss;
}

__device__ __forceinline__ float ciou_f(float x1, float y1, float x2, float y2,
                                        float x1g, float y1g, float x2g, float y2g,
                                        float atan_p, float atan_g) {
    float w1 = x2 - x1, h1 = y2 - y1;
    float wg = x2g - x1g, hg = y2g - y1g;
    float iw = fmaxf(fminf(x2, x2g) - fmaxf(x1, x1g), 0.f);
    float ih = fmaxf(fminf(y2, y2g) - fmaxf(y1, y1g), 0.f);
    float inter = iw * ih;
    float uni = w1 * h1 + wg * hg - inter;
    float iou = inter / (uni + 1e-7f);
    float cw = fmaxf(x2, x2g) - fminf(x1, x1g);
    float ch = fmaxf(y2, y2g) - fminf(y1, y1g);
    float diag = cw * cw + ch * ch + 1e-7f;
    float dx = (x1 + x2 - x1g - x2g) * 0.5f;
    float dy = (y1 + y2 - y1g - y2g) * 0.5f;
    float rho2 = dx * dx + dy * dy;
    float diou = 1.f - iou + rho2 / diag;
    float dd = atan_g - atan_p;
    const float CV = (float)(4.0 / (M_PI * M_PI));
    float v = CV * (dd * dd);
    float alpha = v / (1.f - iou + v + 1e-7f);
    return diou + alpha * v;
}

__device__ __forceinline__ u64 wave_min_u64(u64 k) {
    #pragma unroll
    for (int off = 32; off >= 1; off >>= 1) {
        u64 o = __shfl_xor(k, off);
        k = (o < k) ? o : k;
    }
    return k;
}

// key packs (cost_bits, col). cost >= 0 always -> bit order == value order,
// low word gives the first-index tie-break.
__device__ __forceinline__ u64 pack_key(float v, int idx) {
    return ((u64)__float_as_uint(v) << 32) | (u64)(unsigned)idx;
}

// ---------- the one kernel: fused cost + last-block-per-batch assignment --
// Grid (NSEG, NB), 512 threads. Phase A = R12 fused_kernel verbatim.
// cnt[b] counts finished blocks of batch b; the 132nd runs the batch tail
// (R12 assign_kernel logic, LDS state). cnt[4] gates the final combine.
// cnt[] zeroed by hipMemsetAsync every call -> no ws-carried state.

__global__ __launch_bounds__(512) void mega_kernel(
        const float* __restrict__ outputs, const float* __restrict__ targets,
        float* __restrict__ s0arr, u64* __restrict__ kt1, u64* __restrict__ kt2,
        double* __restrict__ negbuf, double* __restrict__ partials,
        unsigned* __restrict__ cnt, float* __restrict__ out) {
    int sg = blockIdx.x, b = blockIdx.y;
    int tid = threadIdx.x;
    int w = tid >> 6, lane = tid & 63;
    int p0 = sg * 64;
    int nv = (sg == NSEG - 1) ? (NPRED - (NSEG - 1) * 64) : 64;   // 16 or 64

    __shared__ float rows[64 * ROW];        // stride 85 floats -> conflict-free
    __shared__ float s_part[8 * 64];
    __shared__ float s_s0[64];
    __shared__ float s_gt[NGT * 5];
    __shared__ int   s_lab[NGT];
    // tail state
    __shared__ u64    taken[NSEG], poison[NSEG];
    __shared__ int    rmi[NGT];
    __shared__ int    s_midx[NGT];
    __shared__ float  s_siou[NGT], s_cls[NGT], s_adj[NGT];
    __shared__ double s_ns;
    __shared__ int    s_last;

    // ---- Phase A: staging + S0 + cost + top-2 minima (R12 verbatim) ----
    const float4* src4 = (const float4*)(outputs + ((size_t)b * NPRED + p0) * ROW);
    float4* dst4 = (float4*)rows;
    int cnt4 = nv * ROW / 4;                // 1360 or 340, exact
    for (int k = tid; k < cnt4; k += 512) dst4[k] = src4[k];

    if (tid < 32) {
        const float* gt = targets + (size_t)(b * NGT + tid) * ROW;
        float xc = gt[0], yc = gt[1], ww = gt[2], hh = gt[3];
        float x1 = xc - ww * 0.5f, y1 = yc - hh * 0.5f;
        float x2 = xc + ww * 0.5f, y2 = yc + hh * 0.5f;
        float at = atanf((x2 - x1) / (y2 - y1));
        s_gt[tid * 5 + 0] = x1; s_gt[tid * 5 + 1] = y1;
        s_gt[tid * 5 + 2] = x2; s_gt[tid * 5 + 3] = y2;
        s_gt[tid * 5 + 4] = at;
    }
    #pragma unroll
    for (int q = 0; q < 4; ++q) {
        int m = w * 4 + q;
        const float* gt = targets + (size_t)(b * NGT + m) * ROW;
        u64 m1 = __ballot(gt[5 + lane] > 0.5f);
        float v2 = (lane < 16) ? gt[69 + lane] : 0.f;
        u64 m2 = __ballot(v2 > 0.5f);
        if (lane == 0) s_lab[m] = m1 ? (__ffsll(m1) - 1) : (64 + __ffsll(m2) - 1);
    }
    __syncthreads();

    {
        float s = 0.f;
        if (lane < nv) {
            const float* r = rows + lane * ROW;
            int c0 = w * 10;
            #pragma unroll
            for (int c = 0; c < 10; ++c) s += focal_t(r[5 + c0 + c], 0.f);
        }
        s_part[w * 64 + lane] = s;
    }
    __syncthreads();
    if (tid < 64) {
        float s = s_part[tid];
        #pragma unroll
        for (int c = 1; c < 8; ++c) s += s_part[c * 64 + tid];
        s_s0[tid] = s;
        if (tid < nv) s0arr[b * NPRED + p0 + tid] = s;
        double ng = (tid < nv) ? (double)focal_t(rows[tid * ROW + 4], 0.f) : 0.0;
        #pragma unroll
        for (int off = 32; off >= 1; off >>= 1) ng += __shfl_xor(ng, off);
        if (tid == 0) negbuf[b * NSEG + sg] = ng;
    }
    __syncthreads();

    {
        bool valid = lane < nv;
        const float* r = rows + lane * ROW;
        float x1 = 0.f, y1 = 0.f, x2 = 0.f, y2 = 0.f, atan_p = 0.f, S0 = 0.f;
        if (valid) {
            float xc = r[0], yc = r[1], ww = r[2], hh = r[3];
            x1 = xc - ww * 0.5f; y1 = yc - hh * 0.5f;
            x2 = xc + ww * 0.5f; y2 = yc + hh * 0.5f;
            atan_p = atanf((x2 - x1) / (y2 - y1));
            S0 = s_s0[lane];
        }
        #pragma unroll
        for (int q = 0; q < 4; ++q) {
            int m = w * 4 + q;
            const float* gp = s_gt + m * 5;
            float cost = INFINITY;
            if (valid) {
                float cc = ciou_f(x1, y1, x2, y2, gp[0], gp[1], gp[2], gp[3],
                                  atan_p, gp[4]);
                float xl = r[5 + s_lab[m]];
                cost = cc + (S0 - focal_t(xl, 0.f) + focal_t(xl, 1.f)) / 80.f;
            }
            float v = cost;
            #pragma unroll
            for (int off = 32; off >= 1; off >>= 1) v = fminf(v, __shfl_xor(v, off));
            u64 mk1 = __ballot(cost == v);
            int l1 = __ffsll(mk1) - 1;
            int i1 = (l1 < nv) ? (p0 + l1) : NPRED;
            float c2 = (lane == l1) ? INFINITY : cost;
            float v2 = c2;
            #pragma unroll
            for (int off = 32; off >= 1; off >>= 1) v2 = fminf(v2, __shfl_xor(v2, off));
            u64 mk2 = __ballot(c2 == v2);
            int l2 = __ffsll(mk2) - 1;
            int i2 = (l2 < nv) ? (p0 + l2) : NPRED;
            if (lane == 0) {
                kt1[(size_t)(b * NGT + m) * NSEG + sg] = pack_key(v, i1);
                kt2[(size_t)(b * NGT + m) * NSEG + sg] = pack_key(v2, i2);
            }
        }
    }
    __syncthreads();                      // drains this block's global writes

    // ---- last-block election for batch b ----
    if (tid == 0) {
        __threadfence();
        unsigned old = __hip_atomic_fetch_add(&cnt[b], 1u, __ATOMIC_ACQ_REL,
                                              __HIP_MEMORY_SCOPE_AGENT);
        s_last = (old == NSEG - 1) ? 1 : 0;
        if (s_last) __threadfence();
    }
    __syncthreads();
    if (!s_last) return;

    // ================= batch-b tail (132nd block only) =================
    // s_gt / s_lab for batch b already live in this block's LDS.

    if (tid < NSEG) { taken[tid] = 0ull; poison[tid] = 0ull; }

    // rowmin: wave w -> rows w*4..w*4+3, coalesced u64 rowmin over kt1
    #pragma unroll
    for (int q = 0; q < 4; ++q) {
        int row = w * 4 + q;
        const u64* kr = kt1 + ((size_t)b * NGT + row) * NSEG;
        u64 k = kr[lane];
        { u64 v = kr[lane + 64]; if (v < k) k = v; }
        if (lane < NSEG - 128) { u64 v = kr[lane + 128]; if (v < k) k = v; }
        k = wave_min_u64(k);
        if (lane == 0) rmi[row] = (int)(unsigned)(k & 0xffffffffull);
    }
    __syncthreads();

    if (w == 0) {
        // serial assignment for batch b (reference semantics, round-0 note;
        // R12 LDS-state version verbatim)
        const float* Ob = outputs + (size_t)b * NPRED * ROW;
        const float* S0b = s0arr + (size_t)b * NPRED;
        for (int i = 0; i < NGT; ++i) {
            int j1 = rmi[i];
            if ((poison[j1 >> 6] >> (j1 & 63)) & 1ull) {
                // repair: per-seg key = k1 if argmin alive, else k2 if alive,
                // else recompute (both-top2-poisoned: ~never).
                const u64* k1r = kt1 + ((size_t)b * NGT + i) * NSEG;
                const u64* k2r = kt2 + ((size_t)b * NGT + i) * NSEG;
                const float* gp = &s_gt[i * 5];
                int lab = s_lab[i];
                u64 best = ~0ull;
                for (int k0 = 0; k0 < NSEG; k0 += 64) {
                    int s = k0 + lane;
                    u64 eff = ~0ull; bool rc = false;
                    if (s < NSEG) {
                        u64 ka = k1r[s];
                        int ia = (int)(unsigned)(ka & 0xffffffffull);
                        if (!((poison[ia >> 6] >> (ia & 63)) & 1ull)) eff = ka;
                        else {
                            u64 kb = k2r[s];
                            int ib = (int)(unsigned)(kb & 0xffffffffull);
                            if (ib < NPRED && !((poison[ib >> 6] >> (ib & 63)) & 1ull)) eff = kb;
                            else rc = true;
                        }
                    }
                    u64 rm = __ballot(rc);
                    while (rm) {
                        int sgg = k0 + (__ffsll(rm) - 1);
                        rm &= rm - 1;
                        int col = (sgg << 6) + lane;
                        bool cv = (col < NPRED) && !((poison[col >> 6] >> (col & 63)) & 1ull);
                        float vv = INFINITY;
                        if (cv) {
                            const float* pr = Ob + (size_t)col * ROW;
                            float xc = pr[0], yc = pr[1], ww2 = pr[2], hh2 = pr[3];
                            float x1 = xc - ww2 * 0.5f, y1 = yc - hh2 * 0.5f;
                            float x2 = xc + ww2 * 0.5f, y2 = yc + hh2 * 0.5f;
                            float atan_p = atanf((x2 - x1) / (y2 - y1));
                            float cc = ciou_f(x1, y1, x2, y2, gp[0], gp[1], gp[2], gp[3],
                                              atan_p, gp[4]);
                            float xl = pr[5 + lab];
                            vv = cc + (S0b[col] - focal_t(xl, 0.f) + focal_t(xl, 1.f)) / 80.f;
                        }
                        u64 key = pack_key(vv, cv ? col : NPRED);
                        key = wave_min_u64(key);
                        if (s == sgg) eff = key;
                    }
                    if (eff < best) best = eff;
                }
                best = wave_min_u64(best);
                j1 = (int)(unsigned)(best & 0xffffffffull);
            }
            bool tk = (taken[j1 >> 6] >> (j1 & 63)) & 1ull;
            if (!tk) {
                if (lane == 0) { taken[j1 >> 6] |= 1ull << (j1 & 63); s_midx[i] = j1; }
            } else {
                // collision: first free col is in word 0 (<=32 taken bits ever)
                u64 tw = taken[0];
                int bit = __ffsll(~tw) - 1;
                u64 add = (lane == 0) ? (tw & ((bit == 0) ? 0ull : ((1ull << bit) - 1ull))) : 0ull;
                if ((j1 >> 6) == lane) add |= 1ull << (j1 & 63);
                if (add) poison[lane] |= add;
                int u2 = lane + 64;
                if ((j1 >> 6) == u2) poison[u2] |= 1ull << (j1 & 63);
                int u3 = lane + 128;
                if (u3 < NSEG && (j1 >> 6) == u3) poison[u3] |= 1ull << (j1 & 63);
                if (lane == 0) { taken[0] |= 1ull << bit; s_midx[i] = bit; }
            }
        }
    } else if (w == 1) {
        // concurrent: neg partial sum for batch b
        double ng = negbuf[b * NSEG + lane] + negbuf[b * NSEG + 64 + lane]
                  + ((lane < NSEG - 128) ? negbuf[b * NSEG + 128 + lane] : 0.0);
        #pragma unroll
        for (int off = 32; off >= 1; off >>= 1) ng += __shfl_xor(ng, off);
        if (lane == 0) s_ns = ng;
    }
    __syncthreads();

    // finalize partials for batch b
    if (tid < NGT) {
        int m = tid, j = s_midx[m];
        const float* pr = outputs + ((size_t)b * NPRED + j) * ROW;
        float xc = pr[0], yc = pr[1], ww = pr[2], hh = pr[3];
        float x1 = xc - ww * 0.5f, y1 = yc - hh * 0.5f;
        float x2 = xc + ww * 0.5f, y2 = yc + hh * 0.5f;
        float atan_p = atanf((x2 - x1) / (y2 - y1));
        const float* gp = &s_gt[m * 5];
        s_siou[m] = ciou_f(x1, y1, x2, y2, gp[0], gp[1], gp[2], gp[3], atan_p, gp[4]);
        float conf = pr[4];
        s_adj[m] = focal_t(conf, 1.f) - focal_t(conf, 0.f);
    }
    #pragma unroll
    for (int q = 0; q < 4; ++q) {
        int m = w * 4 + q;
        int j = s_midx[m];
        const float* pr = outputs + ((size_t)b * NPRED + j) * ROW;
        const float* gt = targets + ((size_t)b * NGT + m) * ROW;
        float s = focal_t(pr[5 + lane], gt[5 + lane]);
        if (lane < 16) s += focal_t(pr[69 + lane], gt[69 + lane]);
        #pragma unroll
        for (int off = 32; off >= 1; off >>= 1) s += __shfl_xor(s, off);
        if (lane == 0) s_cls[m] = s / 80.f;
    }
    __syncthreads();

    // wave 0: fixed-order per-batch reduce, publish, 4th finisher combines
    if (w == 0) {
        double ss = (lane < NGT) ? (double)s_siou[lane] : 0.0;
        double cs = (lane < NGT) ? (double)s_cls[lane] : 0.0;
        double as = (lane < NGT) ? (double)s_adj[lane] : 0.0;
        #pragma unroll
        for (int off = 32; off >= 1; off >>= 1) {
            ss += __shfl_xor(ss, off);
            cs += __shfl_xor(cs, off);
            as += __shfl_xor(as, off);
        }
        if (lane == 0) {
            partials[b * 4 + 0] = ss;
            partials[b * 4 + 1] = cs;
            partials[b * 4 + 2] = as;
            partials[b * 4 + 3] = s_ns;
            __threadfence();
            unsigned old = __hip_atomic_fetch_add(&cnt[NB], 1u, __ATOMIC_ACQ_REL,
                                                  __HIP_MEMORY_SCOPE_AGENT);
            if (old == NB - 1) {              // last publisher combines
                __threadfence();
                double S = 0.0, C = 0.0, A = 0.0, N = 0.0;
                #pragma unroll
                for (int k = 0; k < NB; ++k) {   // fixed order: deterministic
                    S += __hip_atomic_load(&partials[k * 4 + 0], __ATOMIC_RELAXED, __HIP_MEMORY_SCOPE_AGENT);
                    C += __hip_atomic_load(&partials[k * 4 + 1], __ATOMIC_RELAXED, __HIP_MEMORY_SCOPE_AGENT);
                    A += __hip_atomic_load(&partials[k * 4 + 2], __ATOMIC_RELAXED, __HIP_MEMORY_SCOPE_AGENT);
                    N += __hip_atomic_load(&partials[k * 4 + 3], __ATOMIC_RELAXED, __HIP_MEMORY_SCOPE_AGENT);
                }
                float siou = (float)(S / 128.0);
                float cls  = (float)(C / 128.0);
                float obj  = (float)((N + A) / (double)(NB * NPRED));
                out[0] = 2.0f * siou + 2.0f * obj + 2.0f * cls;
                out[1] = siou;
                out[2] = obj;
                out[3] = cls;
            }
        }
    }
}

// ---------- launch ----------

extern "C" void kernel_launch(void* const* d_in, const int* in_sizes, int n_in,
                              void* d_out, int out_size, void* d_ws, size_t ws_size,
                              hipStream_t stream) {
    const float* outputs = (const float*)d_in[0];
    const float* targets = (const float*)d_in[1];
    float* out = (float*)d_out;

    char* ws = (char*)d_ws;
    double* negbuf = (double*)ws;                     // 4*132*8 = 4224 B
    double* partials = (double*)(ws + 4224);          // 128 B
    unsigned* cnt = (unsigned*)(ws + 4352);           // 5 counters (32 B zeroed)
    float* s0arr = (float*)(ws + 4480);               // 134400 B
    u64* kt1 = (u64*)(ws + 138880);                   // 135168 B
    u64* kt2 = (u64*)(ws + 274048);                   // 135168 B

    hipMemsetAsync(cnt, 0, 32, stream);               // re-arm counters every call

    dim3 g1(NSEG, NB);                                // 132 x 4 segment blocks
    mega_kernel<<<g1, 512, 0, stream>>>(outputs, targets, s0arr, kt1, kt2,
                                        negbuf, partials, cnt, out);
}

// Round 15
// 54.161 us; speedup vs baseline: 1.3443x; 1.3443x over previous
//
#include <hip/hip_runtime.h>
#include <math.h>

#define NB 4
#define NPRED 8400
#define NGT 32
#define NCLS 80
#define ROW 85
#define NSEG 132    // ceil(8400/64); last segment has 16 preds

typedef unsigned long long u64;

// ---------- math helpers (mirror reference fp32 op order) ----------

__device__ __forceinline__ float focal_t(float x, float t) {
    float p = 1.f / (1.f + expf(-x));
    float ce = (fmaxf(x, 0.f) + log1pf(expf(-fabsf(x)))) - x * t; // logaddexp(0,x) - x*t
    float pt = p * t + (1.f - p) * (1.f - t);
    float ompt = 1.f - pt;
    float loss = ce * (ompt * ompt);              // GAMMA=2
    float at = 0.25f * t + 0.75f * (1.f - t);     // ALPHA=0.25
    return at * loss;
}

__device__ __forceinline__ float ciou_f(float x1, float y1, float x2, float y2,
                                        float x1g, float y1g, float x2g, float y2g,
                                        float atan_p, float atan_g) {
    float w1 = x2 - x1, h1 = y2 - y1;
    float wg = x2g - x1g, hg = y2g - y1g;
    float iw = fmaxf(fminf(x2, x2g) - fmaxf(x1, x1g), 0.f);
    float ih = fmaxf(fminf(y2, y2g) - fmaxf(y1, y1g), 0.f);
    float inter = iw * ih;
    float uni = w1 * h1 + wg * hg - inter;
    float iou = inter / (uni + 1e-7f);
    float cw = fmaxf(x2, x2g) - fminf(x1, x1g);
    float ch = fmaxf(y2, y2g) - fminf(y1, y1g);
    float diag = cw * cw + ch * ch + 1e-7f;
    float dx = (x1 + x2 - x1g - x2g) * 0.5f;
    float dy = (y1 + y2 - y1g - y2g) * 0.5f;
    float rho2 = dx * dx + dy * dy;
    float diou = 1.f - iou + rho2 / diag;
    float dd = atan_g - atan_p;
    const float CV = (float)(4.0 / (M_PI * M_PI));
    float v = CV * (dd * dd);
    float alpha = v / (1.f - iou + v + 1e-7f);
    return diou + alpha * v;
}

__device__ __forceinline__ u64 wave_min_u64(u64 k) {
    #pragma unroll
    for (int off = 32; off >= 1; off >>= 1) {
        u64 o = __shfl_xor(k, off);
        k = (o < k) ? o : k;
    }
    return k;
}

// key packs (cost_bits, col). cost >= 0 always -> bit order == value order,
// low word gives the first-index tie-break.
__device__ __forceinline__ u64 pack_key(float v, int idx) {
    return ((u64)__float_as_uint(v) << 32) | (u64)(unsigned)idx;
}

// ---------- K1: fused staging + S0 + cost + TOP-2 segment minima ----------
// Block = (segment sg, batch b), 512 threads. R12 version verbatim.

__global__ __launch_bounds__(512) void fused_kernel(
        const float* __restrict__ outputs, const float* __restrict__ targets,
        float* __restrict__ s0arr, u64* __restrict__ kt1, u64* __restrict__ kt2,
        double* __restrict__ negbuf, float* __restrict__ gtab,
        int* __restrict__ larr) {
    int sg = blockIdx.x, b = blockIdx.y;
    int tid = threadIdx.x;
    int w = tid >> 6, lane = tid & 63;
    int p0 = sg * 64;
    int nv = (sg == NSEG - 1) ? (NPRED - (NSEG - 1) * 64) : 64;   // 16 or 64

    __shared__ float rows[64 * ROW];        // stride 85 floats -> conflict-free
    __shared__ float s_part[8 * 64];
    __shared__ float s_s0[64];
    __shared__ float s_gt[NGT * 5];
    __shared__ int   s_lab[NGT];

    // stage pred rows coalesced (contiguous, 16B-aligned)
    const float4* src4 = (const float4*)(outputs + ((size_t)b * NPRED + p0) * ROW);
    float4* dst4 = (float4*)rows;
    int cnt4 = nv * ROW / 4;                // 1360 or 340, exact
    for (int k = tid; k < cnt4; k += 512) dst4[k] = src4[k];

    // GT boxes (parallel) — same math as reference xywh_to_xyxy + atan
    if (tid < 32) {
        const float* gt = targets + (size_t)(b * NGT + tid) * ROW;
        float xc = gt[0], yc = gt[1], ww = gt[2], hh = gt[3];
        float x1 = xc - ww * 0.5f, y1 = yc - hh * 0.5f;
        float x2 = xc + ww * 0.5f, y2 = yc + hh * 0.5f;
        float at = atanf((x2 - x1) / (y2 - y1));
        s_gt[tid * 5 + 0] = x1; s_gt[tid * 5 + 1] = y1;
        s_gt[tid * 5 + 2] = x2; s_gt[tid * 5 + 3] = y2;
        s_gt[tid * 5 + 4] = at;
        if (sg == 0) {
            float* gp = gtab + (size_t)(b * NGT + tid) * 5;
            gp[0] = x1; gp[1] = y1; gp[2] = x2; gp[3] = y2; gp[4] = at;
        }
    }
    // labels via ballot over the one-hot row (wave w -> 4 GT rows)
    #pragma unroll
    for (int q = 0; q < 4; ++q) {
        int m = w * 4 + q;
        const float* gt = targets + (size_t)(b * NGT + m) * ROW;
        u64 m1 = __ballot(gt[5 + lane] > 0.5f);
        float v2 = (lane < 16) ? gt[69 + lane] : 0.f;
        u64 m2 = __ballot(v2 > 0.5f);
        if (lane == 0) {
            int L = m1 ? (__ffsll(m1) - 1) : (64 + __ffsll(m2) - 1);
            s_lab[m] = L;
            if (sg == 0) larr[b * NGT + m] = L;
        }
    }
    __syncthreads();

    // S0: pred = lane, chunk w covers 10 classes
    {
        float s = 0.f;
        if (lane < nv) {
            const float* r = rows + lane * ROW;
            int c0 = w * 10;
            #pragma unroll
            for (int c = 0; c < 10; ++c) s += focal_t(r[5 + c0 + c], 0.f);
        }
        s_part[w * 64 + lane] = s;
    }
    __syncthreads();
    if (tid < 64) {
        float s = s_part[tid];
        #pragma unroll
        for (int c = 1; c < 8; ++c) s += s_part[c * 64 + tid];
        s_s0[tid] = s;
        if (tid < nv) s0arr[b * NPRED + p0 + tid] = s;
        double ng = (tid < nv) ? (double)focal_t(rows[tid * ROW + 4], 0.f) : 0.0;
        #pragma unroll
        for (int off = 32; off >= 1; off >>= 1) ng += __shfl_xor(ng, off);
        if (tid == 0) negbuf[b * NSEG + sg] = ng;   // direct write, no atomic
    }
    __syncthreads();

    // cost + top-2 segment minima: wave w -> GT rows w*4..w*4+3, lane = pred
    bool valid = lane < nv;
    const float* r = rows + lane * ROW;
    float x1 = 0.f, y1 = 0.f, x2 = 0.f, y2 = 0.f, atan_p = 0.f, S0 = 0.f;
    if (valid) {
        float xc = r[0], yc = r[1], ww = r[2], hh = r[3];
        x1 = xc - ww * 0.5f; y1 = yc - hh * 0.5f;
        x2 = xc + ww * 0.5f; y2 = yc + hh * 0.5f;
        atan_p = atanf((x2 - x1) / (y2 - y1));
        S0 = s_s0[lane];
    }
    #pragma unroll
    for (int q = 0; q < 4; ++q) {
        int m = w * 4 + q;
        const float* gp = s_gt + m * 5;
        float cost = INFINITY;
        if (valid) {
            float cc = ciou_f(x1, y1, x2, y2, gp[0], gp[1], gp[2], gp[3],
                              atan_p, gp[4]);
            float xl = r[5 + s_lab[m]];
            cost = cc + (S0 - focal_t(xl, 0.f) + focal_t(xl, 1.f)) / 80.f;
        }
        // min1 via f32 butterfly + ballot (lowest lane == lowest index)
        float v = cost;
        #pragma unroll
        for (int off = 32; off >= 1; off >>= 1) v = fminf(v, __shfl_xor(v, off));
        u64 mk1 = __ballot(cost == v);
        int l1 = __ffsll(mk1) - 1;
        int i1 = (l1 < nv) ? (p0 + l1) : NPRED;
        // min2: exclude winner lane only
        float c2 = (lane == l1) ? INFINITY : cost;
        float v2 = c2;
        #pragma unroll
        for (int off = 32; off >= 1; off >>= 1) v2 = fminf(v2, __shfl_xor(v2, off));
        u64 mk2 = __ballot(c2 == v2);
        int l2 = __ffsll(mk2) - 1;
        int i2 = (l2 < nv) ? (p0 + l2) : NPRED;
        if (lane == 0) {
            kt1[(size_t)(b * NGT + m) * NSEG + sg] = pack_key(v, i1);
            kt2[(size_t)(b * NGT + m) * NSEG + sg] = pack_key(v2, i2);
        }
    }
}

// ---------- K2: 4 blocks (block = batch), 512 threads --------------------
// R12 assign_kernel with two deltas: (1) collision-free PREFIX SKIP in the
// serial loop (exact: distinct fresh argmins can never hit taken/poison),
// (2) inline fixed-order combine by the last publisher (counter zeroed by
// hipMemsetAsync every call -> no ws-carried state).

__global__ __launch_bounds__(512) void assign_kernel(
        const float* __restrict__ outputs, const float* __restrict__ targets,
        const float* __restrict__ s0arr, const u64* __restrict__ kt1,
        const u64* __restrict__ kt2, const double* __restrict__ negbuf,
        const float* __restrict__ gtab, const int* __restrict__ larr,
        double* __restrict__ partials, unsigned* __restrict__ counter,
        float* __restrict__ out) {
    int b = blockIdx.x;
    int tid = threadIdx.x;
    int w = tid >> 6, lane = tid & 63;

    __shared__ u64    taken[NSEG], poison[NSEG];
    __shared__ float  s_gt[NGT * 5];
    __shared__ int    s_lab[NGT];
    __shared__ int    rmi[NGT];
    __shared__ int    s_midx[NGT];
    __shared__ float  s_siou[NGT], s_cls[NGT], s_adj[NGT];
    __shared__ double s_ns;

    if (tid < NSEG) { taken[tid] = 0ull; poison[tid] = 0ull; }
    if (tid < NGT * 5) s_gt[tid] = gtab[b * NGT * 5 + tid];
    if (tid < NGT) s_lab[tid] = larr[b * NGT + tid];

    // Phase 1: wave w -> rows w*4..w*4+3, coalesced u64 rowmin
    #pragma unroll
    for (int q = 0; q < 4; ++q) {
        int row = w * 4 + q;
        const u64* kr = kt1 + ((size_t)b * NGT + row) * NSEG;
        u64 k = kr[lane];
        { u64 v = kr[lane + 64]; if (v < k) k = v; }
        if (lane < NSEG - 128) { u64 v = kr[lane + 128]; if (v < k) k = v; }
        k = wave_min_u64(k);
        if (lane == 0) rmi[row] = (int)(unsigned)(k & 0xffffffffull);
    }
    __syncthreads();

    if (w == 0) {
        // serial assignment for batch b (reference semantics, round-0 note)
        const float* Ob = outputs + (size_t)b * NPRED * ROW;
        const float* S0b = s0arr + (size_t)b * NPRED;

        // ---- prefix skip: rows before the first duplicate argmin are
        // assigned directly (provably identical: no taken-hit, no poison
        // can exist until a duplicate argmin is processed).
        int r32 = rmi[lane & 31];
        bool dup = false;
        #pragma unroll
        for (int d = 1; d < 32; ++d) {
            int o = __shfl(r32, (lane - d) & 31);
            if ((lane & 31) >= d && o == r32) dup = true;
        }
        u64 dm = __ballot(dup && lane < 32);
        int fd = dm ? (__ffsll(dm) - 1) : NGT;
        if (lane < fd) {
            s_midx[lane] = r32;
            atomicOr(&taken[r32 >> 6], 1ull << (r32 & 63));
        }

        for (int i = fd; i < NGT; ++i) {
            int j1 = rmi[i];
            if ((poison[j1 >> 6] >> (j1 & 63)) & 1ull) {
                // repair: per-seg key = k1 if argmin alive, else k2 if alive,
                // else recompute (both-top2-poisoned: ~never).
                const u64* k1r = kt1 + ((size_t)b * NGT + i) * NSEG;
                const u64* k2r = kt2 + ((size_t)b * NGT + i) * NSEG;
                const float* gp = &s_gt[i * 5];
                int lab = s_lab[i];
                u64 best = ~0ull;
                for (int k0 = 0; k0 < NSEG; k0 += 64) {
                    int s = k0 + lane;
                    u64 eff = ~0ull; bool rc = false;
                    if (s < NSEG) {
                        u64 ka = k1r[s];
                        int ia = (int)(unsigned)(ka & 0xffffffffull);
                        if (!((poison[ia >> 6] >> (ia & 63)) & 1ull)) eff = ka;
                        else {
                            u64 kb = k2r[s];
                            int ib = (int)(unsigned)(kb & 0xffffffffull);
                            if (ib < NPRED && !((poison[ib >> 6] >> (ib & 63)) & 1ull)) eff = kb;
                            else rc = true;
                        }
                    }
                    u64 rm = __ballot(rc);
                    while (rm) {
                        int sgg = k0 + (__ffsll(rm) - 1);
                        rm &= rm - 1;
                        int col = (sgg << 6) + lane;
                        bool cv = (col < NPRED) && !((poison[col >> 6] >> (col & 63)) & 1ull);
                        float vv = INFINITY;
                        if (cv) {
                            const float* pr = Ob + (size_t)col * ROW;
                            float xc = pr[0], yc = pr[1], ww2 = pr[2], hh2 = pr[3];
                            float x1 = xc - ww2 * 0.5f, y1 = yc - hh2 * 0.5f;
                            float x2 = xc + ww2 * 0.5f, y2 = yc + hh2 * 0.5f;
                            float atan_p = atanf((x2 - x1) / (y2 - y1));
                            float cc = ciou_f(x1, y1, x2, y2, gp[0], gp[1], gp[2], gp[3],
                                              atan_p, gp[4]);
                            float xl = pr[5 + lab];
                            vv = cc + (S0b[col] - focal_t(xl, 0.f) + focal_t(xl, 1.f)) / 80.f;
                        }
                        u64 key = pack_key(vv, cv ? col : NPRED);
                        key = wave_min_u64(key);
                        if (s == sgg) eff = key;
                    }
                    if (eff < best) best = eff;
                }
                best = wave_min_u64(best);
                j1 = (int)(unsigned)(best & 0xffffffffull);
            }
            bool tk = (taken[j1 >> 6] >> (j1 & 63)) & 1ull;
            if (!tk) {
                if (lane == 0) { taken[j1 >> 6] |= 1ull << (j1 & 63); s_midx[i] = j1; }
            } else {
                // collision: first free col is in word 0 (<=32 taken bits ever)
                u64 tw = taken[0];
                int bit = __ffsll(~tw) - 1;
                u64 add = (lane == 0) ? (tw & ((bit == 0) ? 0ull : ((1ull << bit) - 1ull))) : 0ull;
                if ((j1 >> 6) == lane) add |= 1ull << (j1 & 63);
                if (add) poison[lane] |= add;
                int u2 = lane + 64;
                if ((j1 >> 6) == u2) poison[u2] |= 1ull << (j1 & 63);
                int u3 = lane + 128;
                if (u3 < NSEG && (j1 >> 6) == u3) poison[u3] |= 1ull << (j1 & 63);
                if (lane == 0) { taken[0] |= 1ull << bit; s_midx[i] = bit; }
            }
        }
    } else if (w == 1) {
        // concurrent: neg partial sum for batch b
        double ng = negbuf[b * NSEG + lane] + negbuf[b * NSEG + 64 + lane]
                  + ((lane < NSEG - 128) ? negbuf[b * NSEG + 128 + lane] : 0.0);
        #pragma unroll
        for (int off = 32; off >= 1; off >>= 1) ng += __shfl_xor(ng, off);
        if (lane == 0) s_ns = ng;
    }
    __syncthreads();

    // Phase 3: finalize partials for batch b
    if (tid < NGT) {               // 32 threads: ciou + obj-adjust per pair
        int m = tid, j = s_midx[m];
        const float* pr = outputs + ((size_t)b * NPRED + j) * ROW;
        float xc = pr[0], yc = pr[1], ww = pr[2], hh = pr[3];
        float x1 = xc - ww * 0.5f, y1 = yc - hh * 0.5f;
        float x2 = xc + ww * 0.5f, y2 = yc + hh * 0.5f;
        float atan_p = atanf((x2 - x1) / (y2 - y1));
        const float* gp = &s_gt[m * 5];
        s_siou[m] = ciou_f(x1, y1, x2, y2, gp[0], gp[1], gp[2], gp[3], atan_p, gp[4]);
        float conf = pr[4];
        s_adj[m] = focal_t(conf, 1.f) - focal_t(conf, 0.f);
    }
    // cls: wave w -> pairs w*4..w*4+3, lane-parallel over classes
    #pragma unroll
    for (int q = 0; q < 4; ++q) {
        int m = w * 4 + q;
        int j = s_midx[m];
        const float* pr = outputs + ((size_t)b * NPRED + j) * ROW;
        const float* gt = targets + ((size_t)b * NGT + m) * ROW;
        float s = focal_t(pr[5 + lane], gt[5 + lane]);
        if (lane < 16) s += focal_t(pr[69 + lane], gt[69 + lane]);
        #pragma unroll
        for (int off = 32; off >= 1; off >>= 1) s += __shfl_xor(s, off);
        if (lane == 0) s_cls[m] = s / 80.f;
    }
    __syncthreads();

    // wave 0: fixed-order per-batch reduce, publish; last publisher combines
    if (w == 0) {
        double ss = (lane < NGT) ? (double)s_siou[lane] : 0.0;
        double cs = (lane < NGT) ? (double)s_cls[lane] : 0.0;
        double as = (lane < NGT) ? (double)s_adj[lane] : 0.0;
        #pragma unroll
        for (int off = 32; off >= 1; off >>= 1) {
            ss += __shfl_xor(ss, off);
            cs += __shfl_xor(cs, off);
            as += __shfl_xor(as, off);
        }
        if (lane == 0) {
            partials[b * 4 + 0] = ss;
            partials[b * 4 + 1] = cs;
            partials[b * 4 + 2] = as;
            partials[b * 4 + 3] = s_ns;
            __threadfence();
            unsigned old = __hip_atomic_fetch_add(counter, 1u, __ATOMIC_ACQ_REL,
                                                  __HIP_MEMORY_SCOPE_AGENT);
            if (old == NB - 1) {              // 4th publisher combines
                __threadfence();
                double S = 0.0, C = 0.0, A = 0.0, N = 0.0;
                #pragma unroll
                for (int k = 0; k < NB; ++k) {   // fixed order: deterministic
                    S += __hip_atomic_load(&partials[k * 4 + 0], __ATOMIC_RELAXED, __HIP_MEMORY_SCOPE_AGENT);
                    C += __hip_atomic_load(&partials[k * 4 + 1], __ATOMIC_RELAXED, __HIP_MEMORY_SCOPE_AGENT);
                    A += __hip_atomic_load(&partials[k * 4 + 2], __ATOMIC_RELAXED, __HIP_MEMORY_SCOPE_AGENT);
                    N += __hip_atomic_load(&partials[k * 4 + 3], __ATOMIC_RELAXED, __HIP_MEMORY_SCOPE_AGENT);
                }
                float siou = (float)(S / 128.0);
                float cls  = (float)(C / 128.0);
                float obj  = (float)((N + A) / (double)(NB * NPRED));
                out[0] = 2.0f * siou + 2.0f * obj + 2.0f * cls;
                out[1] = siou;
                out[2] = obj;
                out[3] = cls;
            }
        }
    }
}

// ---------- launch ----------

extern "C" void kernel_launch(void* const* d_in, const int* in_sizes, int n_in,
                              void* d_out, int out_size, void* d_ws, size_t ws_size,
                              hipStream_t stream) {
    const float* outputs = (const float*)d_in[0];
    const float* targets = (const float*)d_in[1];
    float* out = (float*)d_out;

    char* ws = (char*)d_ws;
    double* negbuf = (double*)ws;                     // 4*132*8 = 4224 B
    float* gtab = (float*)(ws + 4352);                // 2560 B
    int* larr = (int*)(ws + 7040);                    // 512 B
    float* s0arr = (float*)(ws + 7552);               // 134400 B
    u64* kt1 = (u64*)(ws + 141952);                   // 135168 B
    u64* kt2 = (u64*)(ws + 277120);                   // 135168 B
    double* partials = (double*)(ws + 412288);        // 128 B
    unsigned* counter = (unsigned*)(ws + 412416);     // 4 B

    hipMemsetAsync(counter, 0, 4, stream);            // re-arm every call

    dim3 g1(NSEG, NB);                                // 132 x 4 segment blocks
    fused_kernel<<<g1, 512, 0, stream>>>(outputs, targets, s0arr, kt1, kt2,
                                         negbuf, gtab, larr);

    assign_kernel<<<NB, 512, 0, stream>>>(outputs, targets, s0arr, kt1, kt2,
                                          negbuf, gtab, larr, partials,
                                          counter, out);
}

// Round 16
// 50.092 us; speedup vs baseline: 1.4535x; 1.0812x over previous
//
#include <hip/hip_runtime.h>
#include <math.h>

#define NB 4
#define NPRED 8400
#define NGT 32
#define NCLS 80
#define ROW 85
#define NSEG 132    // ceil(8400/64); last segment has 16 preds

typedef unsigned long long u64;

// ---------- math helpers (mirror reference fp32 op order) ----------

__device__ __forceinline__ float focal_t(float x, float t) {
    float p = 1.f / (1.f + expf(-x));
    float ce = (fmaxf(x, 0.f) + log1pf(expf(-fabsf(x)))) - x * t; // logaddexp(0,x) - x*t
    float pt = p * t + (1.f - p) * (1.f - t);
    float ompt = 1.f - pt;
    float loss = ce * (ompt * ompt);              // GAMMA=2
    float at = 0.25f * t + 0.75f * (1.f - t);     // ALPHA=0.25
    return at * loss;
}

__device__ __forceinline__ float ciou_f(float x1, float y1, float x2, float y2,
                                        float x1g, float y1g, float x2g, float y2g,
                                        float atan_p, float atan_g) {
    float w1 = x2 - x1, h1 = y2 - y1;
    float wg = x2g - x1g, hg = y2g - y1g;
    float iw = fmaxf(fminf(x2, x2g) - fmaxf(x1, x1g), 0.f);
    float ih = fmaxf(fminf(y2, y2g) - fmaxf(y1, y1g), 0.f);
    float inter = iw * ih;
    float uni = w1 * h1 + wg * hg - inter;
    float iou = inter / (uni + 1e-7f);
    float cw = fmaxf(x2, x2g) - fminf(x1, x1g);
    float ch = fmaxf(y2, y2g) - fminf(y1, y1g);
    float diag = cw * cw + ch * ch + 1e-7f;
    float dx = (x1 + x2 - x1g - x2g) * 0.5f;
    float dy = (y1 + y2 - y1g - y2g) * 0.5f;
    float rho2 = dx * dx + dy * dy;
    float diou = 1.f - iou + rho2 / diag;
    float dd = atan_g - atan_p;
    const float CV = (float)(4.0 / (M_PI * M_PI));
    float v = CV * (dd * dd);
    float alpha = v / (1.f - iou + v + 1e-7f);
    return diou + alpha * v;
}

__device__ __forceinline__ u64 wave_min_u64(u64 k) {
    #pragma unroll
    for (int off = 32; off >= 1; off >>= 1) {
        u64 o = __shfl_xor(k, off);
        k = (o < k) ? o : k;
    }
    return k;
}

// key packs (cost_bits, col). cost >= 0 always -> bit order == value order,
// low word gives the first-index tie-break.
__device__ __forceinline__ u64 pack_key(float v, int idx) {
    return ((u64)__float_as_uint(v) << 32) | (u64)(unsigned)idx;
}

// ---------- K1: fused staging + S0 + cost + TOP-2 segment minima ----------
// Block = (segment sg, batch b), 512 threads. R12/R15 version; block (0,0)
// additionally zeroes the combine counter (stream order: all of K1 finishes
// before K2 starts -> counter re-armed every call, no ws-carried state).

__global__ __launch_bounds__(512) void fused_kernel(
        const float* __restrict__ outputs, const float* __restrict__ targets,
        float* __restrict__ s0arr, u64* __restrict__ kt1, u64* __restrict__ kt2,
        double* __restrict__ negbuf, float* __restrict__ gtab,
        int* __restrict__ larr, unsigned* __restrict__ counter) {
    int sg = blockIdx.x, b = blockIdx.y;
    int tid = threadIdx.x;
    int w = tid >> 6, lane = tid & 63;
    int p0 = sg * 64;
    int nv = (sg == NSEG - 1) ? (NPRED - (NSEG - 1) * 64) : 64;   // 16 or 64

    __shared__ float rows[64 * ROW];        // stride 85 floats -> conflict-free
    __shared__ float s_part[8 * 64];
    __shared__ float s_s0[64];
    __shared__ float s_gt[NGT * 5];
    __shared__ int   s_lab[NGT];

    if (sg == 0 && b == 0 && tid == 0) *counter = 0u;   // re-armed every call

    // stage pred rows coalesced (contiguous, 16B-aligned)
    const float4* src4 = (const float4*)(outputs + ((size_t)b * NPRED + p0) * ROW);
    float4* dst4 = (float4*)rows;
    int cnt4 = nv * ROW / 4;                // 1360 or 340, exact
    for (int k = tid; k < cnt4; k += 512) dst4[k] = src4[k];

    // GT boxes (parallel) — same math as reference xywh_to_xyxy + atan
    if (tid < 32) {
        const float* gt = targets + (size_t)(b * NGT + tid) * ROW;
        float xc = gt[0], yc = gt[1], ww = gt[2], hh = gt[3];
        float x1 = xc - ww * 0.5f, y1 = yc - hh * 0.5f;
        float x2 = xc + ww * 0.5f, y2 = yc + hh * 0.5f;
        float at = atanf((x2 - x1) / (y2 - y1));
        s_gt[tid * 5 + 0] = x1; s_gt[tid * 5 + 1] = y1;
        s_gt[tid * 5 + 2] = x2; s_gt[tid * 5 + 3] = y2;
        s_gt[tid * 5 + 4] = at;
        if (sg == 0) {
            float* gp = gtab + (size_t)(b * NGT + tid) * 5;
            gp[0] = x1; gp[1] = y1; gp[2] = x2; gp[3] = y2; gp[4] = at;
        }
    }
    // labels via ballot over the one-hot row (wave w -> 4 GT rows)
    #pragma unroll
    for (int q = 0; q < 4; ++q) {
        int m = w * 4 + q;
        const float* gt = targets + (size_t)(b * NGT + m) * ROW;
        u64 m1 = __ballot(gt[5 + lane] > 0.5f);
        float v2 = (lane < 16) ? gt[69 + lane] : 0.f;
        u64 m2 = __ballot(v2 > 0.5f);
        if (lane == 0) {
            int L = m1 ? (__ffsll(m1) - 1) : (64 + __ffsll(m2) - 1);
            s_lab[m] = L;
            if (sg == 0) larr[b * NGT + m] = L;
        }
    }
    __syncthreads();

    // S0: pred = lane, chunk w covers 10 classes
    {
        float s = 0.f;
        if (lane < nv) {
            const float* r = rows + lane * ROW;
            int c0 = w * 10;
            #pragma unroll
            for (int c = 0; c < 10; ++c) s += focal_t(r[5 + c0 + c], 0.f);
        }
        s_part[w * 64 + lane] = s;
    }
    __syncthreads();
    if (tid < 64) {
        float s = s_part[tid];
        #pragma unroll
        for (int c = 1; c < 8; ++c) s += s_part[c * 64 + tid];
        s_s0[tid] = s;
        if (tid < nv) s0arr[b * NPRED + p0 + tid] = s;
        double ng = (tid < nv) ? (double)focal_t(rows[tid * ROW + 4], 0.f) : 0.0;
        #pragma unroll
        for (int off = 32; off >= 1; off >>= 1) ng += __shfl_xor(ng, off);
        if (tid == 0) negbuf[b * NSEG + sg] = ng;   // direct write, no atomic
    }
    __syncthreads();

    // cost + top-2 segment minima: wave w -> GT rows w*4..w*4+3, lane = pred
    bool valid = lane < nv;
    const float* r = rows + lane * ROW;
    float x1 = 0.f, y1 = 0.f, x2 = 0.f, y2 = 0.f, atan_p = 0.f, S0 = 0.f;
    if (valid) {
        float xc = r[0], yc = r[1], ww = r[2], hh = r[3];
        x1 = xc - ww * 0.5f; y1 = yc - hh * 0.5f;
        x2 = xc + ww * 0.5f; y2 = yc + hh * 0.5f;
        atan_p = atanf((x2 - x1) / (y2 - y1));
        S0 = s_s0[lane];
    }
    #pragma unroll
    for (int q = 0; q < 4; ++q) {
        int m = w * 4 + q;
        const float* gp = s_gt + m * 5;
        float cost = INFINITY;
        if (valid) {
            float cc = ciou_f(x1, y1, x2, y2, gp[0], gp[1], gp[2], gp[3],
                              atan_p, gp[4]);
            float xl = r[5 + s_lab[m]];
            cost = cc + (S0 - focal_t(xl, 0.f) + focal_t(xl, 1.f)) / 80.f;
        }
        // min1 via f32 butterfly + ballot (lowest lane == lowest index)
        float v = cost;
        #pragma unroll
        for (int off = 32; off >= 1; off >>= 1) v = fminf(v, __shfl_xor(v, off));
        u64 mk1 = __ballot(cost == v);
        int l1 = __ffsll(mk1) - 1;
        int i1 = (l1 < nv) ? (p0 + l1) : NPRED;
        // min2: exclude winner lane only
        float c2 = (lane == l1) ? INFINITY : cost;
        float v2 = c2;
        #pragma unroll
        for (int off = 32; off >= 1; off >>= 1) v2 = fminf(v2, __shfl_xor(v2, off));
        u64 mk2 = __ballot(c2 == v2);
        int l2 = __ffsll(mk2) - 1;
        int i2 = (l2 < nv) ? (p0 + l2) : NPRED;
        if (lane == 0) {
            kt1[(size_t)(b * NGT + m) * NSEG + sg] = pack_key(v, i1);
            kt2[(size_t)(b * NGT + m) * NSEG + sg] = pack_key(v2, i2);
        }
    }
}

// ---------- K2: 4 blocks (block = batch), 512 threads — R15 verbatim ------
// Prefix skip + repair via top-2 fallback (exact) + inline fixed-order
// combine by the last publisher (counter zeroed by K1 every call).

__global__ __launch_bounds__(512) void assign_kernel(
        const float* __restrict__ outputs, const float* __restrict__ targets,
        const float* __restrict__ s0arr, const u64* __restrict__ kt1,
        const u64* __restrict__ kt2, const double* __restrict__ negbuf,
        const float* __restrict__ gtab, const int* __restrict__ larr,
        double* __restrict__ partials, unsigned* __restrict__ counter,
        float* __restrict__ out) {
    int b = blockIdx.x;
    int tid = threadIdx.x;
    int w = tid >> 6, lane = tid & 63;

    __shared__ u64    taken[NSEG], poison[NSEG];
    __shared__ float  s_gt[NGT * 5];
    __shared__ int    s_lab[NGT];
    __shared__ int    rmi[NGT];
    __shared__ int    s_midx[NGT];
    __shared__ float  s_siou[NGT], s_cls[NGT], s_adj[NGT];
    __shared__ double s_ns;

    if (tid < NSEG) { taken[tid] = 0ull; poison[tid] = 0ull; }
    if (tid < NGT * 5) s_gt[tid] = gtab[b * NGT * 5 + tid];
    if (tid < NGT) s_lab[tid] = larr[b * NGT + tid];

    // Phase 1: wave w -> rows w*4..w*4+3, coalesced u64 rowmin
    #pragma unroll
    for (int q = 0; q < 4; ++q) {
        int row = w * 4 + q;
        const u64* kr = kt1 + ((size_t)b * NGT + row) * NSEG;
        u64 k = kr[lane];
        { u64 v = kr[lane + 64]; if (v < k) k = v; }
        if (lane < NSEG - 128) { u64 v = kr[lane + 128]; if (v < k) k = v; }
        k = wave_min_u64(k);
        if (lane == 0) rmi[row] = (int)(unsigned)(k & 0xffffffffull);
    }
    __syncthreads();

    if (w == 0) {
        // serial assignment for batch b (reference semantics, round-0 note)
        const float* Ob = outputs + (size_t)b * NPRED * ROW;
        const float* S0b = s0arr + (size_t)b * NPRED;

        // prefix skip: rows before the first duplicate argmin are assigned
        // directly (exact: no taken-hit/poison possible until a duplicate).
        int r32 = rmi[lane & 31];
        bool dup = false;
        #pragma unroll
        for (int d = 1; d < 32; ++d) {
            int o = __shfl(r32, (lane - d) & 31);
            if ((lane & 31) >= d && o == r32) dup = true;
        }
        u64 dm = __ballot(dup && lane < 32);
        int fd = dm ? (__ffsll(dm) - 1) : NGT;
        if (lane < fd) {
            s_midx[lane] = r32;
            atomicOr(&taken[r32 >> 6], 1ull << (r32 & 63));
        }

        for (int i = fd; i < NGT; ++i) {
            int j1 = rmi[i];
            if ((poison[j1 >> 6] >> (j1 & 63)) & 1ull) {
                // repair: per-seg key = k1 if argmin alive, else k2 if alive,
                // else recompute (both-top2-poisoned: ~never).
                const u64* k1r = kt1 + ((size_t)b * NGT + i) * NSEG;
                const u64* k2r = kt2 + ((size_t)b * NGT + i) * NSEG;
                const float* gp = &s_gt[i * 5];
                int lab = s_lab[i];
                u64 best = ~0ull;
                for (int k0 = 0; k0 < NSEG; k0 += 64) {
                    int s = k0 + lane;
                    u64 eff = ~0ull; bool rc = false;
                    if (s < NSEG) {
                        u64 ka = k1r[s];
                        int ia = (int)(unsigned)(ka & 0xffffffffull);
                        if (!((poison[ia >> 6] >> (ia & 63)) & 1ull)) eff = ka;
                        else {
                            u64 kb = k2r[s];
                            int ib = (int)(unsigned)(kb & 0xffffffffull);
                            if (ib < NPRED && !((poison[ib >> 6] >> (ib & 63)) & 1ull)) eff = kb;
                            else rc = true;
                        }
                    }
                    u64 rm = __ballot(rc);
                    while (rm) {
                        int sgg = k0 + (__ffsll(rm) - 1);
                        rm &= rm - 1;
                        int col = (sgg << 6) + lane;
                        bool cv = (col < NPRED) && !((poison[col >> 6] >> (col & 63)) & 1ull);
                        float vv = INFINITY;
                        if (cv) {
                            const float* pr = Ob + (size_t)col * ROW;
                            float xc = pr[0], yc = pr[1], ww2 = pr[2], hh2 = pr[3];
                            float x1 = xc - ww2 * 0.5f, y1 = yc - hh2 * 0.5f;
                            float x2 = xc + ww2 * 0.5f, y2 = yc + hh2 * 0.5f;
                            float atan_p = atanf((x2 - x1) / (y2 - y1));
                            float cc = ciou_f(x1, y1, x2, y2, gp[0], gp[1], gp[2], gp[3],
                                              atan_p, gp[4]);
                            float xl = pr[5 + lab];
                            vv = cc + (S0b[col] - focal_t(xl, 0.f) + focal_t(xl, 1.f)) / 80.f;
                        }
                        u64 key = pack_key(vv, cv ? col : NPRED);
                        key = wave_min_u64(key);
                        if (s == sgg) eff = key;
                    }
                    if (eff < best) best = eff;
                }
                best = wave_min_u64(best);
                j1 = (int)(unsigned)(best & 0xffffffffull);
            }
            bool tk = (taken[j1 >> 6] >> (j1 & 63)) & 1ull;
            if (!tk) {
                if (lane == 0) { taken[j1 >> 6] |= 1ull << (j1 & 63); s_midx[i] = j1; }
            } else {
                // collision: first free col is in word 0 (<=32 taken bits ever)
                u64 tw = taken[0];
                int bit = __ffsll(~tw) - 1;
                u64 add = (lane == 0) ? (tw & ((bit == 0) ? 0ull : ((1ull << bit) - 1ull))) : 0ull;
                if ((j1 >> 6) == lane) add |= 1ull << (j1 & 63);
                if (add) poison[lane] |= add;
                int u2 = lane + 64;
                if ((j1 >> 6) == u2) poison[u2] |= 1ull << (j1 & 63);
                int u3 = lane + 128;
                if (u3 < NSEG && (j1 >> 6) == u3) poison[u3] |= 1ull << (j1 & 63);
                if (lane == 0) { taken[0] |= 1ull << bit; s_midx[i] = bit; }
            }
        }
    } else if (w == 1) {
        // concurrent: neg partial sum for batch b
        double ng = negbuf[b * NSEG + lane] + negbuf[b * NSEG + 64 + lane]
                  + ((lane < NSEG - 128) ? negbuf[b * NSEG + 128 + lane] : 0.0);
        #pragma unroll
        for (int off = 32; off >= 1; off >>= 1) ng += __shfl_xor(ng, off);
        if (lane == 0) s_ns = ng;
    }
    __syncthreads();

    // Phase 3: finalize partials for batch b
    if (tid < NGT) {               // 32 threads: ciou + obj-adjust per pair
        int m = tid, j = s_midx[m];
        const float* pr = outputs + ((size_t)b * NPRED + j) * ROW;
        float xc = pr[0], yc = pr[1], ww = pr[2], hh = pr[3];
        float x1 = xc - ww * 0.5f, y1 = yc - hh * 0.5f;
        float x2 = xc + ww * 0.5f, y2 = yc + hh * 0.5f;
        float atan_p = atanf((x2 - x1) / (y2 - y1));
        const float* gp = &s_gt[m * 5];
        s_siou[m] = ciou_f(x1, y1, x2, y2, gp[0], gp[1], gp[2], gp[3], atan_p, gp[4]);
        float conf = pr[4];
        s_adj[m] = focal_t(conf, 1.f) - focal_t(conf, 0.f);
    }
    // cls: wave w -> pairs w*4..w*4+3, lane-parallel over classes
    #pragma unroll
    for (int q = 0; q < 4; ++q) {
        int m = w * 4 + q;
        int j = s_midx[m];
        const float* pr = outputs + ((size_t)b * NPRED + j) * ROW;
        const float* gt = targets + ((size_t)b * NGT + m) * ROW;
        float s = focal_t(pr[5 + lane], gt[5 + lane]);
        if (lane < 16) s += focal_t(pr[69 + lane], gt[69 + lane]);
        #pragma unroll
        for (int off = 32; off >= 1; off >>= 1) s += __shfl_xor(s, off);
        if (lane == 0) s_cls[m] = s / 80.f;
    }
    __syncthreads();

    // wave 0: fixed-order per-batch reduce, publish; last publisher combines
    if (w == 0) {
        double ss = (lane < NGT) ? (double)s_siou[lane] : 0.0;
        double cs = (lane < NGT) ? (double)s_cls[lane] : 0.0;
        double as = (lane < NGT) ? (double)s_adj[lane] : 0.0;
        #pragma unroll
        for (int off = 32; off >= 1; off >>= 1) {
            ss += __shfl_xor(ss, off);
            cs += __shfl_xor(cs, off);
            as += __shfl_xor(as, off);
        }
        if (lane == 0) {
            partials[b * 4 + 0] = ss;
            partials[b * 4 + 1] = cs;
            partials[b * 4 + 2] = as;
            partials[b * 4 + 3] = s_ns;
            __threadfence();
            unsigned old = __hip_atomic_fetch_add(counter, 1u, __ATOMIC_ACQ_REL,
                                                  __HIP_MEMORY_SCOPE_AGENT);
            if (old == NB - 1) {              // 4th publisher combines
                __threadfence();
                double S = 0.0, C = 0.0, A = 0.0, N = 0.0;
                #pragma unroll
                for (int k = 0; k < NB; ++k) {   // fixed order: deterministic
                    S += __hip_atomic_load(&partials[k * 4 + 0], __ATOMIC_RELAXED, __HIP_MEMORY_SCOPE_AGENT);
                    C += __hip_atomic_load(&partials[k * 4 + 1], __ATOMIC_RELAXED, __HIP_MEMORY_SCOPE_AGENT);
                    A += __hip_atomic_load(&partials[k * 4 + 2], __ATOMIC_RELAXED, __HIP_MEMORY_SCOPE_AGENT);
                    N += __hip_atomic_load(&partials[k * 4 + 3], __ATOMIC_RELAXED, __HIP_MEMORY_SCOPE_AGENT);
                }
                float siou = (float)(S / 128.0);
                float cls  = (float)(C / 128.0);
                float obj  = (float)((N + A) / (double)(NB * NPRED));
                out[0] = 2.0f * siou + 2.0f * obj + 2.0f * cls;
                out[1] = siou;
                out[2] = obj;
                out[3] = cls;
            }
        }
    }
}

// ---------- launch ----------

extern "C" void kernel_launch(void* const* d_in, const int* in_sizes, int n_in,
                              void* d_out, int out_size, void* d_ws, size_t ws_size,
                              hipStream_t stream) {
    const float* outputs = (const float*)d_in[0];
    const float* targets = (const float*)d_in[1];
    float* out = (float*)d_out;

    char* ws = (char*)d_ws;
    double* negbuf = (double*)ws;                     // 4*132*8 = 4224 B
    float* gtab = (float*)(ws + 4352);                // 2560 B
    int* larr = (int*)(ws + 7040);                    // 512 B
    float* s0arr = (float*)(ws + 7552);               // 134400 B
    u64* kt1 = (u64*)(ws + 141952);                   // 135168 B
    u64* kt2 = (u64*)(ws + 277120);                   // 135168 B
    double* partials = (double*)(ws + 412288);        // 128 B
    unsigned* counter = (unsigned*)(ws + 412416);     // 4 B (zeroed by K1 each call)

    dim3 g1(NSEG, NB);                                // 132 x 4 segment blocks
    fused_kernel<<<g1, 512, 0, stream>>>(outputs, targets, s0arr, kt1, kt2,
                                         negbuf, gtab, larr, counter);

    assign_kernel<<<NB, 512, 0, stream>>>(outputs, targets, s0arr, kt1, kt2,
                                          negbuf, gtab, larr, partials,
                                          counter, out);
}

// Round 17
// 48.985 us; speedup vs baseline: 1.4863x; 1.0226x over previous
//
#include <hip/hip_runtime.h>
#include <math.h>

#define NB 4
#define NPRED 8400
#define NGT 32
#define NCLS 80
#define ROW 85
#define NSEG 132    // ceil(8400/64); last segment has 16 preds

typedef unsigned long long u64;

// ---------- math helpers (mirror reference fp32 op order) ----------

__device__ __forceinline__ float focal_t(float x, float t) {
    float p = 1.f / (1.f + expf(-x));
    float ce = (fmaxf(x, 0.f) + log1pf(expf(-fabsf(x)))) - x * t; // logaddexp(0,x) - x*t
    float pt = p * t + (1.f - p) * (1.f - t);
    float ompt = 1.f - pt;
    float loss = ce * (ompt * ompt);              // GAMMA=2
    float at = 0.25f * t + 0.75f * (1.f - t);     // ALPHA=0.25
    return at * loss;
}

__device__ __forceinline__ float ciou_f(float x1, float y1, float x2, float y2,
                                        float x1g, float y1g, float x2g, float y2g,
                                        float atan_p, float atan_g) {
    float w1 = x2 - x1, h1 = y2 - y1;
    float wg = x2g - x1g, hg = y2g - y1g;
    float iw = fmaxf(fminf(x2, x2g) - fmaxf(x1, x1g), 0.f);
    float ih = fmaxf(fminf(y2, y2g) - fmaxf(y1, y1g), 0.f);
    float inter = iw * ih;
    float uni = w1 * h1 + wg * hg - inter;
    float iou = inter / (uni + 1e-7f);
    float cw = fmaxf(x2, x2g) - fminf(x1, x1g);
    float ch = fmaxf(y2, y2g) - fminf(y1, y1g);
    float diag = cw * cw + ch * ch + 1e-7f;
    float dx = (x1 + x2 - x1g - x2g) * 0.5f;
    float dy = (y1 + y2 - y1g - y2g) * 0.5f;
    float rho2 = dx * dx + dy * dy;
    float diou = 1.f - iou + rho2 / diag;
    float dd = atan_g - atan_p;
    const float CV = (float)(4.0 / (M_PI * M_PI));
    float v = CV * (dd * dd);
    float alpha = v / (1.f - iou + v + 1e-7f);
    return diou + alpha * v;
}

__device__ __forceinline__ u64 wave_min_u64(u64 k) {
    #pragma unroll
    for (int off = 32; off >= 1; off >>= 1) {
        u64 o = __shfl_xor(k, off);
        k = (o < k) ? o : k;
    }
    return k;
}

// key packs (cost_bits, col). cost >= 0 always -> bit order == value order,
// low word gives the first-index tie-break.
__device__ __forceinline__ u64 pack_key(float v, int idx) {
    return ((u64)__float_as_uint(v) << 32) | (u64)(unsigned)idx;
}

// ---------- K1: fused staging + S0 + cost + TOP-2 segment minima ----------
// Block = (segment sg, batch b), 512 threads. R16 version with the tid<64
// S0-reduce phase folded into the cost phase (identical summation order ->
// identical bits; one fewer barrier, no s_s0 round-trip).

__global__ __launch_bounds__(512) void fused_kernel(
        const float* __restrict__ outputs, const float* __restrict__ targets,
        float* __restrict__ s0arr, u64* __restrict__ kt1, u64* __restrict__ kt2,
        double* __restrict__ negbuf, float* __restrict__ gtab,
        int* __restrict__ larr, unsigned* __restrict__ counter) {
    int sg = blockIdx.x, b = blockIdx.y;
    int tid = threadIdx.x;
    int w = tid >> 6, lane = tid & 63;
    int p0 = sg * 64;
    int nv = (sg == NSEG - 1) ? (NPRED - (NSEG - 1) * 64) : 64;   // 16 or 64

    __shared__ float rows[64 * ROW];        // stride 85 floats -> conflict-free
    __shared__ float s_part[8 * 64];
    __shared__ float s_gt[NGT * 5];
    __shared__ int   s_lab[NGT];

    if (sg == 0 && b == 0 && tid == 0) *counter = 0u;   // re-armed every call

    // stage pred rows coalesced (contiguous, 16B-aligned)
    const float4* src4 = (const float4*)(outputs + ((size_t)b * NPRED + p0) * ROW);
    float4* dst4 = (float4*)rows;
    int cnt4 = nv * ROW / 4;                // 1360 or 340, exact
    for (int k = tid; k < cnt4; k += 512) dst4[k] = src4[k];

    // GT boxes (parallel) — same math as reference xywh_to_xyxy + atan
    if (tid < 32) {
        const float* gt = targets + (size_t)(b * NGT + tid) * ROW;
        float xc = gt[0], yc = gt[1], ww = gt[2], hh = gt[3];
        float x1 = xc - ww * 0.5f, y1 = yc - hh * 0.5f;
        float x2 = xc + ww * 0.5f, y2 = yc + hh * 0.5f;
        float at = atanf((x2 - x1) / (y2 - y1));
        s_gt[tid * 5 + 0] = x1; s_gt[tid * 5 + 1] = y1;
        s_gt[tid * 5 + 2] = x2; s_gt[tid * 5 + 3] = y2;
        s_gt[tid * 5 + 4] = at;
        if (sg == 0) {
            float* gp = gtab + (size_t)(b * NGT + tid) * 5;
            gp[0] = x1; gp[1] = y1; gp[2] = x2; gp[3] = y2; gp[4] = at;
        }
    }
    // labels via ballot over the one-hot row (wave w -> 4 GT rows)
    #pragma unroll
    for (int q = 0; q < 4; ++q) {
        int m = w * 4 + q;
        const float* gt = targets + (size_t)(b * NGT + m) * ROW;
        u64 m1 = __ballot(gt[5 + lane] > 0.5f);
        float v2 = (lane < 16) ? gt[69 + lane] : 0.f;
        u64 m2 = __ballot(v2 > 0.5f);
        if (lane == 0) {
            int L = m1 ? (__ffsll(m1) - 1) : (64 + __ffsll(m2) - 1);
            s_lab[m] = L;
            if (sg == 0) larr[b * NGT + m] = L;
        }
    }
    __syncthreads();

    // S0 partials: pred = lane, chunk w covers 10 classes
    {
        float s = 0.f;
        if (lane < nv) {
            const float* r = rows + lane * ROW;
            int c0 = w * 10;
            #pragma unroll
            for (int c = 0; c < 10; ++c) s += focal_t(r[5 + c0 + c], 0.f);
        }
        s_part[w * 64 + lane] = s;
    }
    __syncthreads();

    // cost + top-2 segment minima: wave w -> GT rows w*4..w*4+3, lane = pred.
    // Each lane re-reduces its pred's S0 from s_part in the SAME c-ascending
    // order as before (bit-identical); wave 0 handles s0arr/negbuf writes.
    bool valid = lane < nv;
    const float* r = rows + lane * ROW;
    float S0 = s_part[lane];
    #pragma unroll
    for (int c = 1; c < 8; ++c) S0 += s_part[c * 64 + lane];

    if (w == 0) {
        if (valid) s0arr[b * NPRED + p0 + lane] = S0;
        double ng = valid ? (double)focal_t(rows[lane * ROW + 4], 0.f) : 0.0;
        #pragma unroll
        for (int off = 32; off >= 1; off >>= 1) ng += __shfl_xor(ng, off);
        if (lane == 0) negbuf[b * NSEG + sg] = ng;   // direct write, no atomic
    }

    float x1 = 0.f, y1 = 0.f, x2 = 0.f, y2 = 0.f, atan_p = 0.f;
    if (valid) {
        float xc = r[0], yc = r[1], ww = r[2], hh = r[3];
        x1 = xc - ww * 0.5f; y1 = yc - hh * 0.5f;
        x2 = xc + ww * 0.5f; y2 = yc + hh * 0.5f;
        atan_p = atanf((x2 - x1) / (y2 - y1));
    }
    #pragma unroll
    for (int q = 0; q < 4; ++q) {
        int m = w * 4 + q;
        const float* gp = s_gt + m * 5;
        float cost = INFINITY;
        if (valid) {
            float cc = ciou_f(x1, y1, x2, y2, gp[0], gp[1], gp[2], gp[3],
                              atan_p, gp[4]);
            float xl = r[5 + s_lab[m]];
            cost = cc + (S0 - focal_t(xl, 0.f) + focal_t(xl, 1.f)) / 80.f;
        }
        // min1 via f32 butterfly + ballot (lowest lane == lowest index)
        float v = cost;
        #pragma unroll
        for (int off = 32; off >= 1; off >>= 1) v = fminf(v, __shfl_xor(v, off));
        u64 mk1 = __ballot(cost == v);
        int l1 = __ffsll(mk1) - 1;
        int i1 = (l1 < nv) ? (p0 + l1) : NPRED;
        // min2: exclude winner lane only
        float c2 = (lane == l1) ? INFINITY : cost;
        float v2 = c2;
        #pragma unroll
        for (int off = 32; off >= 1; off >>= 1) v2 = fminf(v2, __shfl_xor(v2, off));
        u64 mk2 = __ballot(c2 == v2);
        int l2 = __ffsll(mk2) - 1;
        int i2 = (l2 < nv) ? (p0 + l2) : NPRED;
        if (lane == 0) {
            kt1[(size_t)(b * NGT + m) * NSEG + sg] = pack_key(v, i1);
            kt2[(size_t)(b * NGT + m) * NSEG + sg] = pack_key(v2, i2);
        }
    }
}

// ---------- K2: 4 blocks (block = batch), 512 threads — R16 verbatim ------
// Prefix skip + repair via top-2 fallback (exact) + inline fixed-order
// combine by the last publisher (counter zeroed by K1 every call).

__global__ __launch_bounds__(512) void assign_kernel(
        const float* __restrict__ outputs, const float* __restrict__ targets,
        const float* __restrict__ s0arr, const u64* __restrict__ kt1,
        const u64* __restrict__ kt2, const double* __restrict__ negbuf,
        const float* __restrict__ gtab, const int* __restrict__ larr,
        double* __restrict__ partials, unsigned* __restrict__ counter,
        float* __restrict__ out) {
    int b = blockIdx.x;
    int tid = threadIdx.x;
    int w = tid >> 6, lane = tid & 63;

    __shared__ u64    taken[NSEG], poison[NSEG];
    __shared__ float  s_gt[NGT * 5];
    __shared__ int    s_lab[NGT];
    __shared__ int    rmi[NGT];
    __shared__ int    s_midx[NGT];
    __shared__ float  s_siou[NGT], s_cls[NGT], s_adj[NGT];
    __shared__ double s_ns;

    if (tid < NSEG) { taken[tid] = 0ull; poison[tid] = 0ull; }
    if (tid < NGT * 5) s_gt[tid] = gtab[b * NGT * 5 + tid];
    if (tid < NGT) s_lab[tid] = larr[b * NGT + tid];

    // Phase 1: wave w -> rows w*4..w*4+3, coalesced u64 rowmin
    #pragma unroll
    for (int q = 0; q < 4; ++q) {
        int row = w * 4 + q;
        const u64* kr = kt1 + ((size_t)b * NGT + row) * NSEG;
        u64 k = kr[lane];
        { u64 v = kr[lane + 64]; if (v < k) k = v; }
        if (lane < NSEG - 128) { u64 v = kr[lane + 128]; if (v < k) k = v; }
        k = wave_min_u64(k);
        if (lane == 0) rmi[row] = (int)(unsigned)(k & 0xffffffffull);
    }
    __syncthreads();

    if (w == 0) {
        // serial assignment for batch b (reference semantics, round-0 note)
        const float* Ob = outputs + (size_t)b * NPRED * ROW;
        const float* S0b = s0arr + (size_t)b * NPRED;

        // prefix skip: rows before the first duplicate argmin are assigned
        // directly (exact: no taken-hit/poison possible until a duplicate).
        int r32 = rmi[lane & 31];
        bool dup = false;
        #pragma unroll
        for (int d = 1; d < 32; ++d) {
            int o = __shfl(r32, (lane - d) & 31);
            if ((lane & 31) >= d && o == r32) dup = true;
        }
        u64 dm = __ballot(dup && lane < 32);
        int fd = dm ? (__ffsll(dm) - 1) : NGT;
        if (lane < fd) {
            s_midx[lane] = r32;
            atomicOr(&taken[r32 >> 6], 1ull << (r32 & 63));
        }

        for (int i = fd; i < NGT; ++i) {
            int j1 = rmi[i];
            if ((poison[j1 >> 6] >> (j1 & 63)) & 1ull) {
                // repair: per-seg key = k1 if argmin alive, else k2 if alive,
                // else recompute (both-top2-poisoned: ~never).
                const u64* k1r = kt1 + ((size_t)b * NGT + i) * NSEG;
                const u64* k2r = kt2 + ((size_t)b * NGT + i) * NSEG;
                const float* gp = &s_gt[i * 5];
                int lab = s_lab[i];
                u64 best = ~0ull;
                for (int k0 = 0; k0 < NSEG; k0 += 64) {
                    int s = k0 + lane;
                    u64 eff = ~0ull; bool rc = false;
                    if (s < NSEG) {
                        u64 ka = k1r[s];
                        int ia = (int)(unsigned)(ka & 0xffffffffull);
                        if (!((poison[ia >> 6] >> (ia & 63)) & 1ull)) eff = ka;
                        else {
                            u64 kb = k2r[s];
                            int ib = (int)(unsigned)(kb & 0xffffffffull);
                            if (ib < NPRED && !((poison[ib >> 6] >> (ib & 63)) & 1ull)) eff = kb;
                            else rc = true;
                        }
                    }
                    u64 rm = __ballot(rc);
                    while (rm) {
                        int sgg = k0 + (__ffsll(rm) - 1);
                        rm &= rm - 1;
                        int col = (sgg << 6) + lane;
                        bool cv = (col < NPRED) && !((poison[col >> 6] >> (col & 63)) & 1ull);
                        float vv = INFINITY;
                        if (cv) {
                            const float* pr = Ob + (size_t)col * ROW;
                            float xc = pr[0], yc = pr[1], ww2 = pr[2], hh2 = pr[3];
                            float x1 = xc - ww2 * 0.5f, y1 = yc - hh2 * 0.5f;
                            float x2 = xc + ww2 * 0.5f, y2 = yc + hh2 * 0.5f;
                            float atan_p = atanf((x2 - x1) / (y2 - y1));
                            float cc = ciou_f(x1, y1, x2, y2, gp[0], gp[1], gp[2], gp[3],
                                              atan_p, gp[4]);
                            float xl = pr[5 + lab];
                            vv = cc + (S0b[col] - focal_t(xl, 0.f) + focal_t(xl, 1.f)) / 80.f;
                        }
                        u64 key = pack_key(vv, cv ? col : NPRED);
                        key = wave_min_u64(key);
                        if (s == sgg) eff = key;
                    }
                    if (eff < best) best = eff;
                }
                best = wave_min_u64(best);
                j1 = (int)(unsigned)(best & 0xffffffffull);
            }
            bool tk = (taken[j1 >> 6] >> (j1 & 63)) & 1ull;
            if (!tk) {
                if (lane == 0) { taken[j1 >> 6] |= 1ull << (j1 & 63); s_midx[i] = j1; }
            } else {
                // collision: first free col is in word 0 (<=32 taken bits ever)
                u64 tw = taken[0];
                int bit = __ffsll(~tw) - 1;
                u64 add = (lane == 0) ? (tw & ((bit == 0) ? 0ull : ((1ull << bit) - 1ull))) : 0ull;
                if ((j1 >> 6) == lane) add |= 1ull << (j1 & 63);
                if (add) poison[lane] |= add;
                int u2 = lane + 64;
                if ((j1 >> 6) == u2) poison[u2] |= 1ull << (j1 & 63);
                int u3 = lane + 128;
                if (u3 < NSEG && (j1 >> 6) == u3) poison[u3] |= 1ull << (j1 & 63);
                if (lane == 0) { taken[0] |= 1ull << bit; s_midx[i] = bit; }
            }
        }
    } else if (w == 1) {
        // concurrent: neg partial sum for batch b
        double ng = negbuf[b * NSEG + lane] + negbuf[b * NSEG + 64 + lane]
                  + ((lane < NSEG - 128) ? negbuf[b * NSEG + 128 + lane] : 0.0);
        #pragma unroll
        for (int off = 32; off >= 1; off >>= 1) ng += __shfl_xor(ng, off);
        if (lane == 0) s_ns = ng;
    }
    __syncthreads();

    // Phase 3: finalize partials for batch b
    if (tid < NGT) {               // 32 threads: ciou + obj-adjust per pair
        int m = tid, j = s_midx[m];
        const float* pr = outputs + ((size_t)b * NPRED + j) * ROW;
        float xc = pr[0], yc = pr[1], ww = pr[2], hh = pr[3];
        float x1 = xc - ww * 0.5f, y1 = yc - hh * 0.5f;
        float x2 = xc + ww * 0.5f, y2 = yc + hh * 0.5f;
        float atan_p = atanf((x2 - x1) / (y2 - y1));
        const float* gp = &s_gt[m * 5];
        s_siou[m] = ciou_f(x1, y1, x2, y2, gp[0], gp[1], gp[2], gp[3], atan_p, gp[4]);
        float conf = pr[4];
        s_adj[m] = focal_t(conf, 1.f) - focal_t(conf, 0.f);
    }
    // cls: wave w -> pairs w*4..w*4+3, lane-parallel over classes
    #pragma unroll
    for (int q = 0; q < 4; ++q) {
        int m = w * 4 + q;
        int j = s_midx[m];
        const float* pr = outputs + ((size_t)b * NPRED + j) * ROW;
        const float* gt = targets + ((size_t)b * NGT + m) * ROW;
        float s = focal_t(pr[5 + lane], gt[5 + lane]);
        if (lane < 16) s += focal_t(pr[69 + lane], gt[69 + lane]);
        #pragma unroll
        for (int off = 32; off >= 1; off >>= 1) s += __shfl_xor(s, off);
        if (lane == 0) s_cls[m] = s / 80.f;
    }
    __syncthreads();

    // wave 0: fixed-order per-batch reduce, publish; last publisher combines
    if (w == 0) {
        double ss = (lane < NGT) ? (double)s_siou[lane] : 0.0;
        double cs = (lane < NGT) ? (double)s_cls[lane] : 0.0;
        double as = (lane < NGT) ? (double)s_adj[lane] : 0.0;
        #pragma unroll
        for (int off = 32; off >= 1; off >>= 1) {
            ss += __shfl_xor(ss, off);
            cs += __shfl_xor(cs, off);
            as += __shfl_xor(as, off);
        }
        if (lane == 0) {
            partials[b * 4 + 0] = ss;
            partials[b * 4 + 1] = cs;
            partials[b * 4 + 2] = as;
            partials[b * 4 + 3] = s_ns;
            __threadfence();
            unsigned old = __hip_atomic_fetch_add(counter, 1u, __ATOMIC_ACQ_REL,
                                                  __HIP_MEMORY_SCOPE_AGENT);
            if (old == NB - 1) {              // 4th publisher combines
                __threadfence();
                double S = 0.0, C = 0.0, A = 0.0, N = 0.0;
                #pragma unroll
                for (int k = 0; k < NB; ++k) {   // fixed order: deterministic
                    S += __hip_atomic_load(&partials[k * 4 + 0], __ATOMIC_RELAXED, __HIP_MEMORY_SCOPE_AGENT);
                    C += __hip_atomic_load(&partials[k * 4 + 1], __ATOMIC_RELAXED, __HIP_MEMORY_SCOPE_AGENT);
                    A += __hip_atomic_load(&partials[k * 4 + 2], __ATOMIC_RELAXED, __HIP_MEMORY_SCOPE_AGENT);
                    N += __hip_atomic_load(&partials[k * 4 + 3], __ATOMIC_RELAXED, __HIP_MEMORY_SCOPE_AGENT);
                }
                float siou = (float)(S / 128.0);
                float cls  = (float)(C / 128.0);
                float obj  = (float)((N + A) / (double)(NB * NPRED));
                out[0] = 2.0f * siou + 2.0f * obj + 2.0f * cls;
                out[1] = siou;
                out[2] = obj;
                out[3] = cls;
            }
        }
    }
}

// ---------- launch ----------

extern "C" void kernel_launch(void* const* d_in, const int* in_sizes, int n_in,
                              void* d_out, int out_size, void* d_ws, size_t ws_size,
                              hipStream_t stream) {
    const float* outputs = (const float*)d_in[0];
    const float* targets = (const float*)d_in[1];
    float* out = (float*)d_out;

    char* ws = (char*)d_ws;
    double* negbuf = (double*)ws;                     // 4*132*8 = 4224 B
    float* gtab = (float*)(ws + 4352);                // 2560 B
    int* larr = (int*)(ws + 7040);                    // 512 B
    float* s0arr = (float*)(ws + 7552);               // 134400 B
    u64* kt1 = (u64*)(ws + 141952);                   // 135168 B
    u64* kt2 = (u64*)(ws + 277120);                   // 135168 B
    double* partials = (double*)(ws + 412288);        // 128 B
    unsigned* counter = (unsigned*)(ws + 412416);     // 4 B (zeroed by K1 each call)

    dim3 g1(NSEG, NB);                                // 132 x 4 segment blocks
    fused_kernel<<<g1, 512, 0, stream>>>(outputs, targets, s0arr, kt1, kt2,
                                         negbuf, gtab, larr, counter);

    assign_kernel<<<NB, 512, 0, stream>>>(outputs, targets, s0arr, kt1, kt2,
                                          negbuf, gtab, larr, partials,
                                          counter, out);
}